// Round 1
// baseline (206.729 us; speedup 1.0000x reference)
//
#include <hip/hip_runtime.h>
#include <hip/hip_bf16.h>

#define QKVC   2304
#define NHEAD  12
#define NTOK   577
#define NBATCH 16
#define NROWS  (NBATCH * NTOK)   // 9232
#define NPAD   640
#define SCALE  0.125f
#define EPSV   1e-6f

typedef __bf16  bf16x8 __attribute__((ext_vector_type(8)));
typedef float   f32x4  __attribute__((ext_vector_type(4)));

__device__ __forceinline__ unsigned short f2bf(float f) {
    union { float f; unsigned u; } v; v.f = f;
    unsigned r = v.u + 0x7FFFu + ((v.u >> 16) & 1u);   // RNE
    return (unsigned short)(r >> 16);
}
__device__ __forceinline__ unsigned short f2bf_trunc(float f) {
    return (unsigned short)(__float_as_uint(f) >> 16);  // e>=0 only
}
__device__ __forceinline__ f32x4 mfma16(bf16x8 a, bf16x8 b, f32x4 c) {
    return __builtin_amdgcn_mfma_f32_16x16x32_bf16(a, b, c, 0, 0, 0);
}

// async global->LDS, 16B/lane; LDS dest = wave-uniform base + lane*16
#define GLDS16(g, l) __builtin_amdgcn_global_load_lds( \
    (const __attribute__((address_space(1))) unsigned int*)(g), \
    (__attribute__((address_space(3))) unsigned int*)(l), 16, 0, 0)

// ------------------------------------- merged prep: x->bf16 + both W^T
__device__ void transpose_tile(const float* __restrict__ src, unsigned short* __restrict__ dst,
                               int K, int N, int bx, int by, int t) {
    __shared__ unsigned short lt[64 * 72];
    int n0 = bx * 64, k0 = by * 64;
    int kk = t >> 4, nn = (t & 15) * 4;
    for (int i = 0; i < 4; i++) {
        int kr = kk + i * 16;
        float4 v = *(const float4*)&src[(size_t)(k0 + kr) * N + n0 + nn];
        lt[(nn + 0) * 72 + kr] = f2bf(v.x);
        lt[(nn + 1) * 72 + kr] = f2bf(v.y);
        lt[(nn + 2) * 72 + kr] = f2bf(v.z);
        lt[(nn + 3) * 72 + kr] = f2bf(v.w);
    }
    __syncthreads();
    int n = t >> 2, seg = (t & 3) * 16;
    uint4 a = *(uint4*)&lt[n * 72 + seg];
    uint4 b = *(uint4*)&lt[n * 72 + seg + 8];
    *(uint4*)&dst[(size_t)(n0 + n) * K + k0 + seg]     = a;
    *(uint4*)&dst[(size_t)(n0 + n) * K + k0 + seg + 8] = b;
}

#define NCONV (NROWS * 768 / 4 / 256)   // 6927 convert blocks
__global__ void k_prep(const float* __restrict__ x, unsigned short* __restrict__ xb,
                       const float* __restrict__ Wqkv, unsigned short* __restrict__ wqkvt,
                       const float* __restrict__ Wproj, unsigned short* __restrict__ wprojt) {
    int id = blockIdx.x, t = threadIdx.x;
    if (id < NCONV) {
        int idx = id * 256 + t;
        float4 v = ((const float4*)x)[idx];
        ushort4 o;
        o.x = f2bf(v.x); o.y = f2bf(v.y); o.z = f2bf(v.z); o.w = f2bf(v.w);
        ((ushort4*)xb)[idx] = o;
    } else if (id < NCONV + 432) {
        int i2 = id - NCONV;                    // qkv W^T: 36 x 12
        transpose_tile(Wqkv, wqkvt, 768, QKVC, i2 % 36, i2 / 36, t);
    } else {
        int i2 = id - NCONV - 432;              // proj W^T: 12 x 12
        transpose_tile(Wproj, wprojt, 768, 768, i2 % 12, i2 / 12, t);
    }
}

// -------------------------------------------------- 256x128 GEMM, K=768
// RING-4 PIPELINE (T3+T4): BK=32 per step, 24 steps. 4 LDS slots of
// (A 256x32 | B 128x32) bf16 = 24KB each, 96KB total -> 1 block/CU,
// 8 waves (2Mx4N). Step s computes slot s%4 while staging step s+3 into
// slot (s+3)%4 = (s-1)%4, which the top-of-step barrier just freed
// (every wave's ds_reads are lgkmcnt(0)-fenced BEFORE it arrives at the
// next barrier). Steady-state wait is vmcnt(6) -- 2 stage-groups x 3
// glds stay in flight across barriers; tail drains 6->3->0. No vmcnt(0)
// in the main loop (the m233-measured 2-phase drain stall).
// T2 swizzle (rule #21 both-sides): glds LDS dest linear, global k-seg
// pre-XORed per lane; frag reads XOR slot with (row>>1)&3 -> rows 0..7
// cover all 32 banks, b128 reads conflict-free.
// T5: setprio(1) around the 16-MFMA cluster (pays with phase role-split).
template <bool F32OUT>
__global__ __launch_bounds__(512, 2)
void k_gemm(const unsigned short* __restrict__ A, const unsigned short* __restrict__ B,
            const float* __restrict__ bias, void* __restrict__ outp, int Ncols,
            unsigned short* __restrict__ vt) {
    __shared__ unsigned short SL[49152];   // 96KB: A 4x8192 u16 | B @32768 4x4096 u16
    int t = threadIdx.x;
    int lane = t & 63, wave = t >> 6, quad = lane >> 4, l15 = lane & 15;
    int wm = wave >> 2, wn = wave & 3;     // 2 x 4 wave grid; per-wave C = 128x32
    int nT = Ncols >> 7;
    int nwg = gridDim.x;

    // bijective XCD chunk swizzle (m204; nwg=666/222 are not %8==0)
    int q8 = nwg >> 3, r8 = nwg & 7;
    int xcd = blockIdx.x & 7, idx = blockIdx.x >> 3;
    int wg = (xcd < r8 ? xcd * (q8 + 1) : r8 * (q8 + 1) + (xcd - r8) * q8) + idx;
    int m0 = (wg / nT) * 256;              // m-major: XCD streams contiguous A panels
    int n0 = (wg % nT) * 128;

    // staging source pointers, k-segment pre-swizzled (T2 write side)
    int srow = lane >> 2;                        // row within 16-row wave chunk
    int sseg = (lane & 3) ^ ((lane >> 3) & 3);   // XOR swizzle: seg ^ (row>>1)&3
    const unsigned short* gA0 = A + (size_t)(m0 +       wave * 16 + srow) * 768 + sseg * 8;
    const unsigned short* gA1 = A + (size_t)(m0 + 128 + wave * 16 + srow) * 768 + sseg * 8;
    const unsigned short* gB0 = B + (size_t)(n0 +       wave * 16 + srow) * 768 + sseg * 8;

    f32x4 acc[8][2] = {};

    auto STAGE = [&](int sx) {   // 3 glds: A rows 0-127, A rows 128-255, B rows 0-127
        unsigned sa = (unsigned)(sx & 3) * 8192u + (unsigned)wave * 512u;
        unsigned sb = 32768u + (unsigned)(sx & 3) * 4096u + (unsigned)wave * 512u;
        int ko = sx * 32;
        GLDS16(gA0 + ko, &SL[sa]);
        GLDS16(gA1 + ko, &SL[sa + 4096]);
        GLDS16(gB0 + ko, &SL[sb]);
    };

    auto STEP = [&](int s, bool stage) {
        unsigned ab = (unsigned)(s & 3) * 8192u;
        unsigned bb = 32768u + (unsigned)(s & 3) * 4096u;
        unsigned ro = (unsigned)(quad ^ ((l15 >> 1) & 3)) * 8u;  // T2 read side
        bf16x8 af[8], bfr[2];
        #pragma unroll
        for (int i = 0; i < 8; i++)
            af[i]  = *(const bf16x8*)&SL[ab + (unsigned)(wm * 128 + i * 16 + l15) * 32u + ro];
        #pragma unroll
        for (int i = 0; i < 2; i++)
            bfr[i] = *(const bf16x8*)&SL[bb + (unsigned)(wn * 32 + i * 16 + l15) * 32u + ro];
        if (stage) STAGE(s + 3);
        // all my slot-s reads done before I reach the next barrier -> slot
        // (s-1)%4 is provably free for others' glds after that barrier
        asm volatile("s_waitcnt lgkmcnt(0)" ::: "memory");
        __builtin_amdgcn_s_setprio(1);
        #pragma unroll
        for (int mi = 0; mi < 8; mi++)
            #pragma unroll
            for (int ni = 0; ni < 2; ni++)
                acc[mi][ni] = mfma16(af[mi], bfr[ni], acc[mi][ni]);
        __builtin_amdgcn_s_setprio(0);
    };

    STAGE(0); STAGE(1); STAGE(2);           // prime the ring (9 glds in flight)
    for (int s = 0; s < 21; s++) {          // stages targets 3..23
        asm volatile("s_waitcnt vmcnt(6)" ::: "memory");
        asm volatile("s_barrier" ::: "memory");
        STEP(s, true);
    }
    asm volatile("s_waitcnt vmcnt(6)" ::: "memory");
    asm volatile("s_barrier" ::: "memory");
    STEP(21, false);
    asm volatile("s_waitcnt vmcnt(3)" ::: "memory");
    asm volatile("s_barrier" ::: "memory");
    STEP(22, false);
    asm volatile("s_waitcnt vmcnt(0)" ::: "memory");
    asm volatile("s_barrier" ::: "memory");
    STEP(23, false);

    if constexpr (F32OUT) {
        for (int ni = 0; ni < 2; ni++) {
            int col = n0 + wn * 32 + ni * 16 + l15;
            float bv = bias[col];
            for (int mi = 0; mi < 8; mi++) {
                int rowm = m0 + wm * 128 + mi * 16 + quad * 4;
                for (int r = 0; r < 4; r++) {
                    int m = rowm + r;
                    if (m < NROWS)
                        ((float*)outp)[(size_t)m * Ncols + col] = acc[mi][ni][r] + bv;
                }
            }
        }
    } else {
        // repack 256x128 bf16 tile (stride 136 u16) in the ring LDS
        __syncthreads();
        for (int ni = 0; ni < 2; ni++) {
            int colL = wn * 32 + ni * 16 + l15;
            float bv = bias[n0 + colL];
            for (int mi = 0; mi < 8; mi++) {
                int rowL = wm * 128 + mi * 16 + quad * 4;
                for (int r = 0; r < 4; r++)
                    SL[(rowL + r) * 136 + colL] = f2bf(acc[mi][ni][r] + bv);
            }
        }
        __syncthreads();
        if (n0 < 1536) {
            // Q/K cols: full-line row stores to qkvb
            for (int rr = 0; rr < 8; rr++) {
                int row = rr * 32 + (t >> 4);
                int m = m0 + row;
                if (m < NROWS) {
                    uint4 v = *(uint4*)&SL[row * 136 + (t & 15) * 8];
                    *(uint4*)&((unsigned short*)outp)[(size_t)m * Ncols + n0 + (t & 15) * 8] = v;
                }
            }
        } else {
            // V cols: transposed store direct into vt[((b*12+h)*64+d)*NPAD + tok]
            int h0 = (n0 - 1536) >> 6;
            for (int i = 0; i < 16; i++) {
                int c = wave * 16 + i;
                int h = h0 + (c >> 6), d = c & 63;
                for (int half = 0; half < 4; half++) {
                    int lr = half * 64 + lane;
                    int m = m0 + lr;
                    if (m < NROWS) {
                        unsigned bbx = (unsigned)m / 577u;
                        int tok = m - (int)bbx * 577;
                        vt[(((size_t)bbx * NHEAD + h) * 64 + d) * NPAD + tok] =
                            SL[lr * 136 + c];
                    }
                }
            }
        }
    }
}

// --------------------------------------------------------- flash attention
// 128 q-rows per block; Q-frags direct global->VGPR; no max-subtraction
// (scores bounded); row-sum via ones-MFMA. Pad-token V is unwritten poison,
// but P==0 exactly there (pol=0, bf16 trunc) so PV is unaffected.
__global__ __launch_bounds__(256, 4)
void k_attn(const unsigned short* __restrict__ qkv, const unsigned short* __restrict__ vt,
            const float* __restrict__ policy, unsigned short* __restrict__ ao) {
    __shared__ unsigned short Ks[64 * 72];
    __shared__ unsigned short Vs[64 * 72];
    __shared__ unsigned short Ps[4][32 * 72];
    __shared__ float pol[NPAD];
    int t = threadIdx.x;
    int lane = t & 63, wave = t >> 6, quad = lane >> 4, l15 = lane & 15;
    int b = blockIdx.z, h = blockIdx.y, qt = blockIdx.x;
    const unsigned short* qbase = qkv + (size_t)(b * NTOK) * QKVC + h * 64;
    const unsigned short* kbase = qkv + (size_t)(b * NTOK) * QKVC + 768 + h * 64;
    const unsigned short* vbase = vt + (size_t)(b * NHEAD + h) * 64 * NPAD;

    for (int i = t; i < NPAD; i += 256)
        pol[i] = (i < NTOK) ? policy[b * NTOK + i] : 0.f;

    bf16x8 qf[2][2];
    for (int mi = 0; mi < 2; mi++) {
        const unsigned short* qp =
            qbase + (size_t)(qt * 128 + mi * 64 + wave * 16 + l15) * QKVC + quad * 8;
        qf[mi][0] = *(const bf16x8*)qp;
        qf[mi][1] = *(const bf16x8*)(qp + 32);
    }
    bf16x8 onesf;
    for (int j = 0; j < 8; j++) onesf[j] = (__bf16)1.0f;
    f32x4 o[2][4] = {};
    f32x4 ls[2] = {};
    int rowtok0[2];
    for (int mi = 0; mi < 2; mi++)
        rowtok0[mi] = qt * 128 + mi * 64 + wave * 16 + quad * 4;
    __syncthreads();

    for (int kt = 0; kt < 10; kt++) {
        int key0 = kt * 64;
        for (int i = t; i < 512; i += 256) {
            int row = i >> 3, seg = (i & 7) * 8;
            *(uint4*)&Ks[row * 72 + seg] = *(const uint4*)&kbase[(size_t)(key0 + row) * QKVC + seg];
            *(uint4*)&Vs[row * 72 + seg] = *(const uint4*)&vbase[(size_t)row * NPAD + key0 + seg];
        }
        __syncthreads();

        for (int ci = 0; ci < 4; ci++) {
            bf16x8 kf0 = *(const bf16x8*)&Ks[(ci * 16 + l15) * 72 + quad * 8];
            bf16x8 kf1 = *(const bf16x8*)&Ks[(ci * 16 + l15) * 72 + 32 + quad * 8];
            int col = key0 + ci * 16 + l15;
            float pc = pol[col];
            for (int mi = 0; mi < 2; mi++) {
                f32x4 a = {};
                a = mfma16(qf[mi][0], kf0, a);
                a = mfma16(qf[mi][1], kf1, a);
                for (int r = 0; r < 4; r++) {
                    float ap = (col == rowtok0[mi] + r) ? 1.f : pc;
                    float e = __expf(a[r] * SCALE) * ap;
                    Ps[wave][(mi * 16 + quad * 4 + r) * 72 + ci * 16 + l15] = f2bf_trunc(e);
                }
            }
        }
        __asm__ volatile("s_waitcnt lgkmcnt(0)" ::: "memory");
        bf16x8 pf[2][2];
        for (int mi = 0; mi < 2; mi++) {
            pf[mi][0] = *(const bf16x8*)&Ps[wave][(mi * 16 + l15) * 72 + quad * 8];
            pf[mi][1] = *(const bf16x8*)&Ps[wave][(mi * 16 + l15) * 72 + 32 + quad * 8];
            ls[mi] = mfma16(pf[mi][0], onesf, ls[mi]);
            ls[mi] = mfma16(pf[mi][1], onesf, ls[mi]);
        }
        for (int di = 0; di < 4; di++) {
            bf16x8 vf0 = *(const bf16x8*)&Vs[(di * 16 + l15) * 72 + quad * 8];
            bf16x8 vf1 = *(const bf16x8*)&Vs[(di * 16 + l15) * 72 + 32 + quad * 8];
            for (int mi = 0; mi < 2; mi++) {
                o[mi][di] = mfma16(pf[mi][0], vf0, o[mi][di]);
                o[mi][di] = mfma16(pf[mi][1], vf1, o[mi][di]);
            }
        }
        __syncthreads();
    }

    for (int mi = 0; mi < 2; mi++) {
        for (int r = 0; r < 4; r++) {
            int tok = rowtok0[mi] + r;
            if (tok < NTOK) {
                float inv = __builtin_amdgcn_rcpf(ls[mi][r] + EPSV);
                for (int di = 0; di < 4; di++) {
                    float val = o[mi][di][r] * inv;
                    ao[((size_t)(b * NTOK + tok)) * 768 + h * 64 + di * 16 + l15] = f2bf(val);
                }
            }
        }
    }
}

// ------------------------------------------------------------------ launch
extern "C" void kernel_launch(void* const* d_in, const int* in_sizes, int n_in,
                              void* d_out, int out_size, void* d_ws, size_t ws_size,
                              hipStream_t stream) {
    const float* x      = (const float*)d_in[0];
    const float* policy = (const float*)d_in[1];
    const float* Wqkv   = (const float*)d_in[2];
    const float* bqkv   = (const float*)d_in[3];
    const float* Wproj  = (const float*)d_in[4];
    const float* bproj  = (const float*)d_in[5];
    float* out = (float*)d_out;

    // workspace carve. xb/ao alias (xb dead before ao written). GEMM A-staging
    // over-reads up to ~370KB past xb/ao end (absorbed by wqkvt+wprojt);
    // attention Q/K over-reads <=300KB past qkvb (absorbed by vt).
    unsigned short* p = (unsigned short*)d_ws;
    unsigned short* xb     = p;
    unsigned short* ao     = p; p += (size_t)NROWS * 768;
    unsigned short* wqkvt  = p; p += (size_t)QKVC * 768;
    unsigned short* wprojt = p; p += (size_t)768 * 768;
    unsigned short* qkvb   = p; p += (size_t)NROWS * QKVC;
    unsigned short* vt     = p; p += (size_t)NBATCH * NHEAD * 64 * NPAD;

    int mT = (NROWS + 255) / 256;   // 37 m-tiles of 256

    k_prep<<<NCONV + 432 + 144, 256, 0, stream>>>(x, xb, Wqkv, wqkvt, Wproj, wprojt);
    k_gemm<false><<<mT * (QKVC / 128), 512, 0, stream>>>(
        xb, wqkvt, bqkv, (void*)qkvb, QKVC, vt);
    k_attn<<<dim3(NPAD / 128, NHEAD, NBATCH), 256, 0, stream>>>(qkvb, vt, policy, ao);
    k_gemm<true><<<mT * (768 / 128), 512, 0, stream>>>(
        ao, wprojt, bproj, (void*)out, 768, nullptr);
}

// Round 3
// 191.017 us; speedup vs baseline: 1.0823x; 1.0823x over previous
//
#include <hip/hip_runtime.h>
#include <hip/hip_bf16.h>

#define QKVC   2304
#define NHEAD  12
#define NTOK   577
#define NBATCH 16
#define NROWS  (NBATCH * NTOK)   // 9232 = 16*577 -> exactly 577 m-tiles of 16
#define NPAD   640
#define SCALE  0.125f
#define EPSV   1e-6f
#define KT     24                // K=768 -> 24 k-tiles of 32
#define CH     512               // u16 per chunk: 16 rows x 32 cols, 1KB

typedef __bf16  bf16x8 __attribute__((ext_vector_type(8)));
typedef float   f32x4  __attribute__((ext_vector_type(4)));

__device__ __forceinline__ unsigned short f2bf(float f) {
    union { float f; unsigned u; } v; v.f = f;
    unsigned r = v.u + 0x7FFFu + ((v.u >> 16) & 1u);   // RNE
    return (unsigned short)(r >> 16);
}
__device__ __forceinline__ unsigned short f2bf_trunc(float f) {
    return (unsigned short)(__float_as_uint(f) >> 16);  // e>=0 only
}
__device__ __forceinline__ unsigned pack2bf(float a, float b) {
    return (unsigned)f2bf(a) | ((unsigned)f2bf(b) << 16);
}
__device__ __forceinline__ f32x4 mfma16(bf16x8 a, bf16x8 b, f32x4 c) {
    return __builtin_amdgcn_mfma_f32_16x16x32_bf16(a, b, c, 0, 0, 0);
}

// async global->LDS, 16B/lane; LDS dest = wave-uniform base + lane*16
#define GLDS16(g, l) __builtin_amdgcn_global_load_lds( \
    (const __attribute__((address_space(1))) unsigned int*)(g), \
    (__attribute__((address_space(3))) unsigned int*)(l), 16, 0, 0)

// TILED OPERAND LAYOUT: operand[mtile][ktile] = 1KB chunk of 16 rows x 32
// cols bf16, row-major within chunk, with the T2 seg-swizzle PRE-BAKED:
// chunk[r][q*8..] = src[row r][(q ^ ((r>>1)&3))*8..]. A glds of one chunk
// (lane*16B) is 1024 CONTIGUOUS bytes -> minimal L1/TA transactions, and
// the LDS image equals the old verified layout exactly (linear rows x 32,
// swizzled segs), so the fragment-read side is unchanged.

// ------------------------------------- merged prep: x->tiled bf16 + both W^T
__device__ void transpose_tile(const float* __restrict__ src, unsigned short* __restrict__ dst,
                               int N, int bx, int by, int t) {
    // src: [768][N] f32; dst: tiled chunks [ntile][KT][16][32] u16 (swizzled)
    __shared__ unsigned short lt[64 * 72];
    int n0 = bx * 64, k0 = by * 64;
    int kk = t >> 4, nn = (t & 15) * 4;
    for (int i = 0; i < 4; i++) {
        int kr = kk + i * 16;
        float4 v = *(const float4*)&src[(size_t)(k0 + kr) * N + n0 + nn];
        lt[(nn + 0) * 72 + kr] = f2bf(v.x);
        lt[(nn + 1) * 72 + kr] = f2bf(v.y);
        lt[(nn + 2) * 72 + kr] = f2bf(v.z);
        lt[(nn + 3) * 72 + kr] = f2bf(v.w);
    }
    __syncthreads();
    int n = t >> 2;              // 0..63
    int ks = (t & 3) * 16;       // k offset within the 64-wide tile
    int gn = n0 + n;
    int ntile = gn >> 4, r = gn & 15, s = (r >> 1) & 3;
    for (int j = 0; j < 2; j++) {
        int k = k0 + ks + j * 8;             // global k of this 8-u16 seg
        int kt = k >> 5;
        int q = ((k >> 3) & 3) ^ s;          // baked swizzle
        uint4 v = *(uint4*)&lt[n * 72 + ks + j * 8];
        *(uint4*)&dst[((size_t)ntile * KT + kt) * CH + r * 32 + q * 8] = v;
    }
}

#define NCHUNK (577 * KT)            // 13848 x-chunks
#define CONVB  ((NCHUNK + 15) / 16)  // 866 conversion blocks (16 chunks each)
__global__ void k_prep(const float* __restrict__ x, unsigned short* __restrict__ xbt,
                       const float* __restrict__ Wqkv, unsigned short* __restrict__ wqkvt,
                       const float* __restrict__ Wproj, unsigned short* __restrict__ wprojt) {
    int id = blockIdx.x, t = threadIdx.x;
    if (id < CONVB) {
        int cid = id * 16 + (t >> 4);
        if (cid < NCHUNK) {
            int r = t & 15;
            int mt = cid / KT, kt = cid - mt * KT;
            const float* src = x + ((size_t)mt * 16 + r) * 768 + kt * 32;
            int s = (r >> 1) & 3;
            unsigned short* dst = xbt + (size_t)cid * CH + r * 32;
            #pragma unroll
            for (int q = 0; q < 4; q++) {
                int g = q ^ s;               // runtime addr on the LOAD (no scratch array)
                float4 v0 = *(const float4*)(src + g * 8);
                float4 v1 = *(const float4*)(src + g * 8 + 4);
                uint4 u;
                u.x = pack2bf(v0.x, v0.y);
                u.y = pack2bf(v0.z, v0.w);
                u.z = pack2bf(v1.x, v1.y);
                u.w = pack2bf(v1.z, v1.w);
                *(uint4*)(dst + q * 8) = u;
            }
        }
    } else if (id < CONVB + 432) {
        int i2 = id - CONVB;                    // qkv W^T: 36 x 12
        transpose_tile(Wqkv, wqkvt, QKVC, i2 % 36, i2 / 36, t);
    } else {
        int i2 = id - CONVB - 432;              // proj W^T: 12 x 12
        transpose_tile(Wproj, wprojt, 768, i2 % 12, i2 / 12, t);
    }
}

// -------------------------------------------------- 256x128 GEMM, K=768
// Ring-3 (72KB LDS -> 2 blocks/CU), BK=32, 24 steps, counted vmcnt(3),
// prefetch distance 2. STAGE is 3 glds/wave of CONTIGUOUS 1KB chunks
// (tiled operand layout) -- this round's lever: glds transaction count.
// Slot safety: step s reads slot s%3 (own glds drained by vmcnt(3) +
// barrier); stage(s+2) targets slot (s+2)%3 == (s-1)%3, whose readers all
// fenced lgkmcnt(0) before the barrier at top of step s.
template <bool F32OUT>
__global__ __launch_bounds__(512, 2)
void k_gemm(const unsigned short* __restrict__ A, const unsigned short* __restrict__ B,
            const float* __restrict__ bias, void* __restrict__ outp, int Ncols,
            unsigned short* __restrict__ vt) {
    __shared__ unsigned short SL[36864];   // 72KB: A 3x8192 u16 | B @24576 3x4096 u16
    int t = threadIdx.x;
    int lane = t & 63, wave = t >> 6, quad = lane >> 4, l15 = lane & 15;
    int wm = wave >> 2, wn = wave & 3;     // 2 x 4 wave grid; per-wave C = 128x32
    int nT = Ncols >> 7;
    int nwg = gridDim.x;

    // bijective XCD chunk swizzle (m204; nwg=666/222 are not %8==0)
    int q8 = nwg >> 3, r8 = nwg & 7;
    int xcd = blockIdx.x & 7, idx = blockIdx.x >> 3;
    int wg = (xcd < r8 ? xcd * (q8 + 1) : r8 * (q8 + 1) + (xcd - r8) * q8) + idx;
    int m0 = (wg / nT) * 256;              // m-major: XCD streams contiguous A panels
    int n0 = (wg % nT) * 128;

    // chunk-tiled staging pointers: wave w owns m-tiles (m0/16+w, m0/16+8+w)
    // and n-tile (n0/16+w); each glds reads one contiguous 1KB chunk.
    const unsigned short* gA0 = A + ((size_t)((m0 >> 4) + wave) * KT) * CH + lane * 8;
    const unsigned short* gA1 = gA0 + (size_t)8 * KT * CH;
    const unsigned short* gB0 = B + ((size_t)((n0 >> 4) + wave) * KT) * CH + lane * 8;

    f32x4 acc[8][2] = {};

    auto STAGE = [&](int sx, unsigned slot) {   // 3 contiguous-1KB glds
        unsigned sa = slot * 8192u + (unsigned)wave * 512u;
        unsigned sb = 24576u + slot * 4096u + (unsigned)wave * 512u;
        GLDS16(gA0 + sx * CH, &SL[sa]);
        GLDS16(gA1 + sx * CH, &SL[sa + 4096]);
        GLDS16(gB0 + sx * CH, &SL[sb]);
    };

    auto STEP = [&](unsigned slot, int sx, unsigned sslot, bool stage) {
        unsigned ab = slot * 8192u;
        unsigned bb = 24576u + slot * 4096u;
        unsigned ro = (unsigned)(quad ^ ((l15 >> 1) & 3)) * 8u;  // T2 read side
        bf16x8 af[8], bfr[2];
        #pragma unroll
        for (int i = 0; i < 8; i++)
            af[i]  = *(const bf16x8*)&SL[ab + (unsigned)(wm * 128 + i * 16 + l15) * 32u + ro];
        #pragma unroll
        for (int i = 0; i < 2; i++)
            bfr[i] = *(const bf16x8*)&SL[bb + (unsigned)(wn * 32 + i * 16 + l15) * 32u + ro];
        if (stage) STAGE(sx, sslot);
        asm volatile("s_waitcnt lgkmcnt(0)" ::: "memory");
        __builtin_amdgcn_s_setprio(1);
        #pragma unroll
        for (int mi = 0; mi < 8; mi++)
            #pragma unroll
            for (int ni = 0; ni < 2; ni++)
                acc[mi][ni] = mfma16(af[mi], bfr[ni], acc[mi][ni]);
        __builtin_amdgcn_s_setprio(0);
    };

    STAGE(0, 0); STAGE(1, 1);               // prime (6 glds in flight)
    for (int s = 0; s < 23; s++) {          // steps 0..22
        asm volatile("s_waitcnt vmcnt(3)" ::: "memory");
        asm volatile("s_barrier" ::: "memory");
        STEP((unsigned)(s % 3), s + 2, (unsigned)((s + 2) % 3), s < 22);
    }
    asm volatile("s_waitcnt vmcnt(0)" ::: "memory");
    asm volatile("s_barrier" ::: "memory");
    STEP(2u, 0, 0u, false);                 // step 23 (23%3 == 2)

    if constexpr (F32OUT) {
        for (int ni = 0; ni < 2; ni++) {
            int col = n0 + wn * 32 + ni * 16 + l15;
            float bv = bias[col];
            for (int mi = 0; mi < 8; mi++) {
                int rowm = m0 + wm * 128 + mi * 16 + quad * 4;
                for (int r = 0; r < 4; r++) {
                    int m = rowm + r;
                    if (m < NROWS)
                        ((float*)outp)[(size_t)m * Ncols + col] = acc[mi][ni][r] + bv;
                }
            }
        }
    } else {
        // repack 256x128 bf16 tile (stride 136 u16) in the ring LDS (34816 u16 fits)
        __syncthreads();
        for (int ni = 0; ni < 2; ni++) {
            int colL = wn * 32 + ni * 16 + l15;
            float bv = bias[n0 + colL];
            for (int mi = 0; mi < 8; mi++) {
                int rowL = wm * 128 + mi * 16 + quad * 4;
                for (int r = 0; r < 4; r++)
                    SL[(rowL + r) * 136 + colL] = f2bf(acc[mi][ni][r] + bv);
            }
        }
        __syncthreads();
        if (n0 < 1536) {
            // Q/K cols: full-line row stores to qkvb
            for (int rr = 0; rr < 8; rr++) {
                int row = rr * 32 + (t >> 4);
                int m = m0 + row;
                if (m < NROWS) {
                    uint4 v = *(uint4*)&SL[row * 136 + (t & 15) * 8];
                    *(uint4*)&((unsigned short*)outp)[(size_t)m * Ncols + n0 + (t & 15) * 8] = v;
                }
            }
        } else {
            // V cols: transposed store direct into vt[((b*12+h)*64+d)*NPAD + tok]
            int h0 = (n0 - 1536) >> 6;
            for (int i = 0; i < 16; i++) {
                int c = wave * 16 + i;
                int h = h0 + (c >> 6), d = c & 63;
                for (int half = 0; half < 4; half++) {
                    int lr = half * 64 + lane;
                    int m = m0 + lr;
                    if (m < NROWS) {
                        unsigned bbx = (unsigned)m / 577u;
                        int tok = m - (int)bbx * 577;
                        vt[(((size_t)bbx * NHEAD + h) * 64 + d) * NPAD + tok] =
                            SL[lr * 136 + c];
                    }
                }
            }
        }
    }
}

// --------------------------------------------------------- flash attention
// 128 q-rows per block; Q-frags direct global->VGPR; no max-subtraction
// (scores bounded); row-sum via ones-MFMA. Pad-token V is unwritten poison,
// but P==0 exactly there (pol=0, bf16 trunc) so PV is unaffected.
// Output is written in the TILED chunk layout (proj GEMM's A operand).
__global__ __launch_bounds__(256, 4)
void k_attn(const unsigned short* __restrict__ qkv, const unsigned short* __restrict__ vt,
            const float* __restrict__ policy, unsigned short* __restrict__ ao) {
    __shared__ unsigned short Ks[64 * 72];
    __shared__ unsigned short Vs[64 * 72];
    __shared__ unsigned short Ps[4][32 * 72];
    __shared__ float pol[NPAD];
    int t = threadIdx.x;
    int lane = t & 63, wave = t >> 6, quad = lane >> 4, l15 = lane & 15;
    int b = blockIdx.z, h = blockIdx.y, qt = blockIdx.x;
    const unsigned short* qbase = qkv + (size_t)(b * NTOK) * QKVC + h * 64;
    const unsigned short* kbase = qkv + (size_t)(b * NTOK) * QKVC + 768 + h * 64;
    const unsigned short* vbase = vt + (size_t)(b * NHEAD + h) * 64 * NPAD;

    for (int i = t; i < NPAD; i += 256)
        pol[i] = (i < NTOK) ? policy[b * NTOK + i] : 0.f;

    bf16x8 qf[2][2];
    for (int mi = 0; mi < 2; mi++) {
        const unsigned short* qp =
            qbase + (size_t)(qt * 128 + mi * 64 + wave * 16 + l15) * QKVC + quad * 8;
        qf[mi][0] = *(const bf16x8*)qp;
        qf[mi][1] = *(const bf16x8*)(qp + 32);
    }
    bf16x8 onesf;
    for (int j = 0; j < 8; j++) onesf[j] = (__bf16)1.0f;
    f32x4 o[2][4] = {};
    f32x4 ls[2] = {};
    int rowtok0[2];
    for (int mi = 0; mi < 2; mi++)
        rowtok0[mi] = qt * 128 + mi * 64 + wave * 16 + quad * 4;
    __syncthreads();

    for (int kt = 0; kt < 10; kt++) {
        int key0 = kt * 64;
        for (int i = t; i < 512; i += 256) {
            int row = i >> 3, seg = (i & 7) * 8;
            *(uint4*)&Ks[row * 72 + seg] = *(const uint4*)&kbase[(size_t)(key0 + row) * QKVC + seg];
            *(uint4*)&Vs[row * 72 + seg] = *(const uint4*)&vbase[(size_t)row * NPAD + key0 + seg];
        }
        __syncthreads();

        for (int ci = 0; ci < 4; ci++) {
            bf16x8 kf0 = *(const bf16x8*)&Ks[(ci * 16 + l15) * 72 + quad * 8];
            bf16x8 kf1 = *(const bf16x8*)&Ks[(ci * 16 + l15) * 72 + 32 + quad * 8];
            int col = key0 + ci * 16 + l15;
            float pc = pol[col];
            for (int mi = 0; mi < 2; mi++) {
                f32x4 a = {};
                a = mfma16(qf[mi][0], kf0, a);
                a = mfma16(qf[mi][1], kf1, a);
                for (int r = 0; r < 4; r++) {
                    float ap = (col == rowtok0[mi] + r) ? 1.f : pc;
                    float e = __expf(a[r] * SCALE) * ap;
                    Ps[wave][(mi * 16 + quad * 4 + r) * 72 + ci * 16 + l15] = f2bf_trunc(e);
                }
            }
        }
        __asm__ volatile("s_waitcnt lgkmcnt(0)" ::: "memory");
        bf16x8 pf[2][2];
        for (int mi = 0; mi < 2; mi++) {
            pf[mi][0] = *(const bf16x8*)&Ps[wave][(mi * 16 + l15) * 72 + quad * 8];
            pf[mi][1] = *(const bf16x8*)&Ps[wave][(mi * 16 + l15) * 72 + 32 + quad * 8];
            ls[mi] = mfma16(pf[mi][0], onesf, ls[mi]);
            ls[mi] = mfma16(pf[mi][1], onesf, ls[mi]);
        }
        for (int di = 0; di < 4; di++) {
            bf16x8 vf0 = *(const bf16x8*)&Vs[(di * 16 + l15) * 72 + quad * 8];
            bf16x8 vf1 = *(const bf16x8*)&Vs[(di * 16 + l15) * 72 + 32 + quad * 8];
            for (int mi = 0; mi < 2; mi++) {
                o[mi][di] = mfma16(pf[mi][0], vf0, o[mi][di]);
                o[mi][di] = mfma16(pf[mi][1], vf1, o[mi][di]);
            }
        }
        __syncthreads();
    }

    for (int mi = 0; mi < 2; mi++) {
        for (int r = 0; r < 4; r++) {
            int tok = rowtok0[mi] + r;
            if (tok < NTOK) {
                float inv = __builtin_amdgcn_rcpf(ls[mi][r] + EPSV);
                int m = b * NTOK + tok;
                int mt = m >> 4, rr = m & 15, s = (rr >> 1) & 3;
                unsigned short* dst = ao + ((size_t)mt * KT) * CH + rr * 32;
                for (int di = 0; di < 4; di++) {
                    int k = h * 64 + di * 16 + l15;
                    int kt2 = k >> 5;
                    int q = ((k >> 3) & 3) ^ s;
                    dst[(size_t)kt2 * CH + q * 8 + (l15 & 7)] =
                        f2bf(o[mi][di][r] * inv);
                }
            }
        }
    }
}

// ------------------------------------------------------------------ launch
extern "C" void kernel_launch(void* const* d_in, const int* in_sizes, int n_in,
                              void* d_out, int out_size, void* d_ws, size_t ws_size,
                              hipStream_t stream) {
    const float* x      = (const float*)d_in[0];
    const float* policy = (const float*)d_in[1];
    const float* Wqkv   = (const float*)d_in[2];
    const float* bqkv   = (const float*)d_in[3];
    const float* Wproj  = (const float*)d_in[4];
    const float* bproj  = (const float*)d_in[5];
    float* out = (float*)d_out;

    // workspace carve. xb/ao alias (xb dead before ao written); both use the
    // tiled chunk layout (577*24 chunks = NROWS*768 u16 exactly). GEMM
    // A-staging over-reads up to ~370KB past xb/ao end for m-tiles 577..591
    // (absorbed by wqkvt+wprojt, masked in epilogue); attention Q/K
    // over-reads <=300KB past qkvb (absorbed by vt).
    unsigned short* p = (unsigned short*)d_ws;
    unsigned short* xb     = p;
    unsigned short* ao     = p; p += (size_t)NROWS * 768;
    unsigned short* wqkvt  = p; p += (size_t)QKVC * 768;
    unsigned short* wprojt = p; p += (size_t)768 * 768;
    unsigned short* qkvb   = p; p += (size_t)NROWS * QKVC;
    unsigned short* vt     = p; p += (size_t)NBATCH * NHEAD * 64 * NPAD;

    int mT = (NROWS + 255) / 256;   // 37 m-tiles of 256

    k_prep<<<CONVB + 432 + 144, 256, 0, stream>>>(x, xb, Wqkv, wqkvt, Wproj, wprojt);
    k_gemm<false><<<mT * (QKVC / 128), 512, 0, stream>>>(
        xb, wqkvt, bqkv, (void*)qkvb, QKVC, vt);
    k_attn<<<dim3(NPAD / 128, NHEAD, NBATCH), 256, 0, stream>>>(qkvb, vt, policy, ao);
    k_gemm<true><<<mT * (768 / 128), 512, 0, stream>>>(
        ao, wprojt, bproj, (void*)out, 768, nullptr);
}